// Round 6
// baseline (378.340 us; speedup 1.0000x reference)
//
#include <hip/hip_runtime.h>
#include <hip/hip_bf16.h>
#include <stdint.h>

#define T_LEN   16384
#define HID     1024
#define KDIM    1024
#define CHUNK   64
#define NCHUNK  256   // T_LEN / CHUNK

typedef __bf16 bf16x8 __attribute__((ext_vector_type(8)));
typedef float  f32x4  __attribute__((ext_vector_type(4)));

__device__ inline ushort f2bf(float f) {
  union { float f; uint32_t u; } v; v.f = f;
  uint32_t r = v.u + 0x7FFF + ((v.u >> 16) & 1);   // RNE
  return (ushort)(r >> 16);
}
__device__ inline float bf2f(ushort u) {
  union { uint32_t u; float f; } v; v.u = ((uint32_t)u) << 16;
  return v.f;
}

__device__ inline void gload16(const void* g, void* l) {
  __builtin_amdgcn_global_load_lds(
      (const __attribute__((address_space(1))) void*)g,
      (__attribute__((address_space(3))) void*)l, 16, 0, 0);
}

// ============ fused prep: weights (z=0..4), lambda (z=5), convX (z>=6) ========
// All jobs independent: eg is computed inline in z=0/1 (no cross-z dependency).
__global__ __launch_bounds__(256) void prep_all(
    const float* __restrict__ inputs,
    const float* __restrict__ nu_log, const float* __restrict__ theta_log,
    const float* __restrict__ gamma_log,
    const float* __restrict__ Bre, const float* __restrict__ Bim,
    const float* __restrict__ Cre, const float* __restrict__ Cim,
    const float* __restrict__ D,
    ushort* __restrict__ Xbf,
    ushort* __restrict__ BreT, ushort* __restrict__ BimT,
    ushort* __restrict__ CreB, ushort* __restrict__ CimB,
    ushort* __restrict__ DT,
    float* __restrict__ lam_re, float* __restrict__ lam_im) {
  __shared__ float tile[32][33];
  const int z = blockIdx.z;
  const int tid = threadIdx.x;
  if (z >= 6) {                       // convX: fp32 -> bf16, float4
    size_t b = (size_t)(z - 6) * 1024 + blockIdx.y * 32 + blockIdx.x;
    size_t i = (b * 256 + tid) * 4;
    float4 v = *(const float4*)(inputs + i);
    ushort4 o;
    o.x = f2bf(v.x); o.y = f2bf(v.y); o.z = f2bf(v.z); o.w = f2bf(v.w);
    *(ushort4*)(Xbf + i) = o;
    return;
  }
  if (z == 5) {                       // lambda prep (4 blocks of work)
    if (blockIdx.y == 0 && blockIdx.x < 4) {
      int h = blockIdx.x * 256 + tid;
      float mag = expf(-expf(nu_log[h]));
      float th  = expf(theta_log[h]);
      lam_re[h] = mag * cosf(th);
      lam_im[h] = mag * sinf(th);
    }
    return;
  }
  if (z == 2 || z == 3) {             // C convert (+negate im)
    const float* src = (z == 2) ? Cre : Cim;
    ushort* dst = (z == 2) ? CreB : CimB;
    float s = (z == 2) ? 1.0f : -1.0f;
    size_t base = ((size_t)blockIdx.y * 32 + (tid >> 3)) * 1024 +
                  blockIdx.x * 32 + (tid & 7) * 4;
    float4 v = *(const float4*)(src + base);
    ushort4 o;
    o.x = f2bf(v.x * s); o.y = f2bf(v.y * s);
    o.z = f2bf(v.z * s); o.w = f2bf(v.w * s);
    *(ushort4*)(dst + base) = o;
    return;
  }
  // z=0,1: B transpose + inline exp(gamma) scale; z=4: D transpose
  const float* src = (z == 0) ? Bre : (z == 1) ? Bim : D;
  ushort* dst = (z == 0) ? BreT : (z == 1) ? BimT : DT;
  bool scaled = (z < 2);
  int bx = blockIdx.x * 32;   // n-block
  int by = blockIdx.y * 32;   // k-block
  int tx = tid & 31, ty = tid >> 5;
#pragma unroll
  for (int r = 0; r < 32; r += 8)
    tile[ty + r][tx] = src[(size_t)(by + ty + r) * 1024 + bx + tx];
  __syncthreads();
  float sc = scaled ? expf(gamma_log[by + tx]) : 1.0f;
#pragma unroll
  for (int r = 0; r < 32; r += 8)
    dst[(size_t)(bx + ty + r) * 1024 + by + tx] = f2bf(tile[tx][ty + r] * sc);
}

// ============ 256x256 SINGLE-BARRIER 8-phase MFMA GEMM (round-5, unchanged) ====
#define BAR()   __builtin_amdgcn_s_barrier()
#define FEN()   asm volatile("" ::: "memory")
#define VM4()   asm volatile("s_waitcnt vmcnt(4)" ::: "memory")
#define VM0()   asm volatile("s_waitcnt vmcnt(0)" ::: "memory")
#define PBAR()  do { FEN(); BAR(); FEN(); } while (0)

#define STAGE_HALF(G, LDA, R0, K0, LT, HALF)                         \
  do {                                                               \
    _Pragma("unroll")                                                \
    for (int is_ = 0; is_ < 2; ++is_) {                              \
      int seg_ = w * 2 + is_;                                        \
      int gr_ = (R0) + (HALF) * 128 + seg_ * 8 + (l >> 3);           \
      int gc_ = (K0) + (((l & 7) ^ (l >> 3)) << 3);                  \
      gload16((G) + (size_t)gr_ * (LDA) + gc_,                       \
              (LT) + (HALF) * 8192 + seg_ * 512);                    \
    }                                                                \
  } while (0)

#define DS_A(QM, BUF)                                                \
  do {                                                               \
    _Pragma("unroll")                                                \
    for (int m_ = 0; m_ < 4; ++m_) {                                 \
      int r_ = (wr * 128 + ((QM) * 4 + m_) * 16 + lo) * 64;          \
      a[m_][0] = *(const bf16x8*)((BUF) + r_ + c0us);                \
      a[m_][1] = *(const bf16x8*)((BUF) + r_ + c1us);                \
    }                                                                \
  } while (0)

#define DS_B(QN, BUF, REG)                                           \
  do {                                                               \
    _Pragma("unroll")                                                \
    for (int n_ = 0; n_ < 2; ++n_) {                                 \
      int r_ = (wc * 64 + ((QN) * 2 + n_) * 16 + lo) * 64;           \
      REG[n_][0] = *(const bf16x8*)((BUF) + r_ + c0us);              \
      REG[n_][1] = *(const bf16x8*)((BUF) + r_ + c1us);              \
    }                                                                \
  } while (0)

#define MFMA_Q(QM, QN, REG)                                          \
  do {                                                               \
    __builtin_amdgcn_s_setprio(1);                                   \
    _Pragma("unroll")                                                \
    for (int m_ = 0; m_ < 4; ++m_)                                   \
      _Pragma("unroll")                                              \
      for (int n_ = 0; n_ < 2; ++n_) {                               \
        f32x4* ac_ = &acc[(QM) * 4 + m_][(QN) * 2 + n_];             \
        *ac_ = __builtin_amdgcn_mfma_f32_16x16x32_bf16(              \
            a[m_][0], REG[n_][0], *ac_, 0, 0, 0);                    \
        *ac_ = __builtin_amdgcn_mfma_f32_16x16x32_bf16(              \
            a[m_][1], REG[n_][1], *ac_, 0, 0, 0);                    \
      }                                                              \
    __builtin_amdgcn_s_setprio(0);                                   \
  } while (0)

template<int NSEG>
__device__ __forceinline__ void gemm256_1bar(
    const ushort* Ap0, int ld0, const ushort* Bp0,
    const ushort* Ap1, int ld1, const ushort* Bp1,
    const ushort* Ap2, int ld2, const ushort* Bp2,
    ushort* lds, int row0, int col0,
    int w, int l, int wr, int wc, int lo, int c0us, int c1us,
    f32x4 (&acc)[8][4]) {
  ushort* A0 = lds;
  ushort* A1 = lds + 16384;
  ushort* B0 = lds + 32768;
  ushort* B1 = lds + 49152;
  bf16x8 a[4][2], bq0[2][2], bq1[2][2];
  const int NT = NSEG * 16;

  auto stageA = [&](int t, ushort* buf) {
    const ushort* A; int lda;
    if constexpr (NSEG == 1) { A = Ap0; lda = ld0; }
    else {
      if (t < 16)      { A = Ap0; lda = ld0; }
      else if (t < 32) { A = Ap1; lda = ld1; }
      else             { A = Ap2; lda = ld2; }
    }
    const int kk = (t & 15) * 64;
    STAGE_HALF(A, lda, row0, kk, buf, 0);
    STAGE_HALF(A, lda, row0, kk, buf, 1);
  };
  auto stageB = [&](int t, ushort* buf) {
    const ushort* B;
    if constexpr (NSEG == 1) { B = Bp0; }
    else {
      if (t < 16)      B = Bp0;
      else if (t < 32) B = Bp1;
      else             B = Bp2;
    }
    const int kk = (t & 15) * 64;
    STAGE_HALF(B, 1024, col0, kk, buf, 0);
    STAGE_HALF(B, 1024, col0, kk, buf, 1);
  };

  stageA(0, A0); stageB(0, B0); stageB(1, B1);
  VM4(); PBAR();

#pragma unroll 1
  for (int j = 0; j < NT / 2; ++j) {
    const int t1 = 2 * j + 1, t2 = 2 * j + 2, t3 = 2 * j + 3;
    const bool st = (t2 < NT);
    // P1
    DS_A(0, A0); DS_B(0, B0, bq0);
    stageA(t1, A1);
    PBAR(); MFMA_Q(0, 0, bq0);
    // P2
    DS_B(1, B0, bq1);
    PBAR(); MFMA_Q(0, 1, bq1);
    // P3
    DS_A(1, A0);
    PBAR(); MFMA_Q(1, 0, bq0);
    // P4
    if (st) { stageB(t2, B0); VM4(); } else { VM0(); }
    PBAR(); MFMA_Q(1, 1, bq1);
    // P5
    DS_A(0, A1); DS_B(0, B1, bq0);
    if (st) stageA(t2, A0);
    PBAR(); MFMA_Q(0, 0, bq0);
    // P6
    DS_B(1, B1, bq1);
    PBAR(); MFMA_Q(0, 1, bq1);
    // P7
    DS_A(1, A1);
    PBAR(); MFMA_Q(1, 0, bq0);
    // P8
    if (st) { stageB(t3, B1); VM4(); }
    PBAR(); MFMA_Q(1, 1, bq1);
  }
}

// ---------------- Bu GEMM: X @ [BreT;BimT]^T -> bf16 T x 2048 ----------------
__global__ __launch_bounds__(512, 2) void gemm_bu(
    const ushort* __restrict__ A, const ushort* __restrict__ B,
    ushort* __restrict__ O) {
  __shared__ __align__(16) ushort lds[65536];
  const int tid = threadIdx.x;
  const int w = tid >> 6, l = tid & 63;
  const int wr = w >> 2, wc = w & 3;
  const int lo = l & 15, q = l >> 4;
  const int xorv = (lo & 7) << 4;
  const int c0us = ((q * 16) ^ xorv) >> 1;
  const int c1us = ((64 + q * 16) ^ xorv) >> 1;
  const int id = blockIdx.x;
  const int xcd = id & 7, slot = id >> 3;
  const int row0 = (xcd * 8 + (slot >> 3)) * 256;
  const int col0 = (slot & 7) * 256;
  f32x4 acc[8][4];
#pragma unroll
  for (int m = 0; m < 8; ++m)
#pragma unroll
    for (int n = 0; n < 4; ++n) acc[m][n] = (f32x4){0.f, 0.f, 0.f, 0.f};
  gemm256_1bar<1>(A, 1024, B, A, 1024, B, A, 1024, B,
                  lds, row0, col0, w, l, wr, wc, lo, c0us, c1us, acc);
  const int rowb = row0 + wr * 128, colb = col0 + wc * 64;
#pragma unroll
  for (int m = 0; m < 8; ++m)
#pragma unroll
    for (int n = 0; n < 4; ++n) {
      int col = colb + n * 16 + lo;
#pragma unroll
      for (int r = 0; r < 4; ++r)
        O[(size_t)(rowb + m * 16 + q * 4 + r) * 2048 + col] = f2bf(acc[m][n][r]);
    }
}

// ---------------- out = Hre@Cre^T + Him@(-Cim)^T + X@D^T ----------------
__global__ __launch_bounds__(512, 2) void gemm3(
    const ushort* __restrict__ Hall,
    const ushort* __restrict__ CreB, const ushort* __restrict__ CimB,
    const ushort* __restrict__ X,    const ushort* __restrict__ DT,
    float* __restrict__ O) {
  __shared__ __align__(16) ushort lds[65536];
  const int tid = threadIdx.x;
  const int w = tid >> 6, l = tid & 63;
  const int wr = w >> 2, wc = w & 3;
  const int lo = l & 15, q = l >> 4;
  const int xorv = (lo & 7) << 4;
  const int c0us = ((q * 16) ^ xorv) >> 1;
  const int c1us = ((64 + q * 16) ^ xorv) >> 1;
  const int id = blockIdx.x;
  const int xcd = id & 7, slot = id >> 3;
  const int row0 = (xcd * 8 + (slot >> 2)) * 256;
  const int col0 = (slot & 3) * 256;
  f32x4 acc[8][4];
#pragma unroll
  for (int m = 0; m < 8; ++m)
#pragma unroll
    for (int n = 0; n < 4; ++n) acc[m][n] = (f32x4){0.f, 0.f, 0.f, 0.f};
  gemm256_1bar<3>(Hall, 2048, CreB,
                  Hall + 1024, 2048, CimB,
                  X, 1024, DT,
                  lds, row0, col0, w, l, wr, wc, lo, c0us, c1us, acc);
  const int rowb = row0 + wr * 128, colb = col0 + wc * 64;
#pragma unroll
  for (int m = 0; m < 8; ++m)
#pragma unroll
    for (int n = 0; n < 4; ++n) {
      int col = colb + n * 16 + lo;
#pragma unroll
      for (int r = 0; r < 4; ++r)
        O[(size_t)(rowb + m * 16 + q * 4 + r) * HID + col] = acc[m][n][r];
    }
}

// ---------------- scan pass A: chunk sums (uint2, 4 h/thread) -----------------
// Block c covers the FULL h-width: 256 threads x uint2 = whole 4 KB row; the
// block walks its 256 KB chunk fully contiguously.
__global__ __launch_bounds__(256) void scan_sums(
    const ushort* __restrict__ Bu,
    const float* __restrict__ lam_re, const float* __restrict__ lam_im,
    float* __restrict__ Sre, float* __restrict__ Sim) {
  const int c = blockIdx.x, tid = threadIdx.x;
  const int h0 = tid * 4;
  float lr[4], li[4], hr[4], hi[4];
#pragma unroll
  for (int j = 0; j < 4; ++j) {
    lr[j] = lam_re[h0 + j]; li[j] = lam_im[h0 + j];
    hr[j] = 0.f; hi[j] = 0.f;
  }
  const uint2* R = (const uint2*)Bu;       // row = 512 uint2 (re 0..255, im 256..511)
  size_t rb = (size_t)c * CHUNK * 512;
#pragma unroll 8
  for (int t = 0; t < CHUNK; ++t) {
    uint2 re = R[rb + (size_t)t * 512 + tid];
    uint2 im = R[rb + (size_t)t * 512 + 256 + tid];
    float br[4] = { bf2f((ushort)re.x), bf2f((ushort)(re.x >> 16)),
                    bf2f((ushort)re.y), bf2f((ushort)(re.y >> 16)) };
    float bi[4] = { bf2f((ushort)im.x), bf2f((ushort)(im.x >> 16)),
                    bf2f((ushort)im.y), bf2f((ushort)(im.y >> 16)) };
#pragma unroll
    for (int j = 0; j < 4; ++j) {
      float nr = fmaf(lr[j], hr[j], fmaf(-li[j], hi[j], br[j]));
      float ni = fmaf(lr[j], hi[j], fmaf(li[j], hr[j], bi[j]));
      hr[j] = nr; hi[j] = ni;
    }
  }
  *(float4*)(Sre + (size_t)c * HID + h0) = (float4){hr[0], hr[1], hr[2], hr[3]};
  *(float4*)(Sim + (size_t)c * HID + h0) = (float4){hi[0], hi[1], hi[2], hi[3]};
}

// ---------------- scan pass B: inline carry prefix + emit bf16 Hall -----------
// scan_carry folded in: each block computes its own exclusive prefix over
// Sre/Sim (L2-resident; <=255 complex FMAs on a dependent chain).
__global__ __launch_bounds__(256) void scan_emit(
    const ushort* __restrict__ Bu,
    const float* __restrict__ lam_re, const float* __restrict__ lam_im,
    const float* __restrict__ Sre, const float* __restrict__ Sim,
    ushort* __restrict__ Hall) {
  const int c = blockIdx.x, tid = threadIdx.x;
  const int h0 = tid * 4;
  float lr[4], li[4], pr[4], pi[4], hr[4], hi[4];
#pragma unroll
  for (int j = 0; j < 4; ++j) {
    lr[j] = lam_re[h0 + j]; li[j] = lam_im[h0 + j];
    float ar = lr[j], ai = li[j];          // lambda^64 via 6 squarings
#pragma unroll
    for (int s = 0; s < 6; ++s) {
      float nr = ar * ar - ai * ai;
      float ni = 2.f * ar * ai;
      ar = nr; ai = ni;
    }
    pr[j] = ar; pi[j] = ai;
    hr[j] = 0.f; hi[j] = 0.f;
  }
  for (int cp = 0; cp < c; ++cp) {         // exclusive prefix carry
    float4 sr = *(const float4*)(Sre + (size_t)cp * HID + h0);
    float4 si = *(const float4*)(Sim + (size_t)cp * HID + h0);
    float srv[4] = {sr.x, sr.y, sr.z, sr.w};
    float siv[4] = {si.x, si.y, si.z, si.w};
#pragma unroll
    for (int j = 0; j < 4; ++j) {
      float nr = fmaf(pr[j], hr[j], fmaf(-pi[j], hi[j], srv[j]));
      float ni = fmaf(pr[j], hi[j], fmaf(pi[j], hr[j], siv[j]));
      hr[j] = nr; hi[j] = ni;
    }
  }
  const uint2* R = (const uint2*)Bu;
  uint2* Q = (uint2*)Hall;
  size_t rb = (size_t)c * CHUNK * 512;
#pragma unroll 4
  for (int t = 0; t < CHUNK; ++t) {
    uint2 re = R[rb + (size_t)t * 512 + tid];
    uint2 im = R[rb + (size_t)t * 512 + 256 + tid];
    float br[4] = { bf2f((ushort)re.x), bf2f((ushort)(re.x >> 16)),
                    bf2f((ushort)re.y), bf2f((ushort)(re.y >> 16)) };
    float bi[4] = { bf2f((ushort)im.x), bf2f((ushort)(im.x >> 16)),
                    bf2f((ushort)im.y), bf2f((ushort)(im.y >> 16)) };
#pragma unroll
    for (int j = 0; j < 4; ++j) {
      float nr = fmaf(lr[j], hr[j], fmaf(-li[j], hi[j], br[j]));
      float ni = fmaf(lr[j], hi[j], fmaf(li[j], hr[j], bi[j]));
      hr[j] = nr; hi[j] = ni;
    }
    uint2 oR, oI;
    oR.x = (uint)f2bf(hr[0]) | ((uint)f2bf(hr[1]) << 16);
    oR.y = (uint)f2bf(hr[2]) | ((uint)f2bf(hr[3]) << 16);
    oI.x = (uint)f2bf(hi[0]) | ((uint)f2bf(hi[1]) << 16);
    oI.y = (uint)f2bf(hi[2]) | ((uint)f2bf(hi[3]) << 16);
    Q[rb + (size_t)t * 512 + tid] = oR;
    Q[rb + (size_t)t * 512 + 256 + tid] = oI;
  }
}

extern "C" void kernel_launch(void* const* d_in, const int* in_sizes, int n_in,
                              void* d_out, int out_size, void* d_ws, size_t ws_size,
                              hipStream_t stream) {
  const float* inputs    = (const float*)d_in[0];
  const float* nu_log    = (const float*)d_in[1];
  const float* theta_log = (const float*)d_in[2];
  const float* gamma_log = (const float*)d_in[3];
  const float* B_re      = (const float*)d_in[4];
  const float* B_im      = (const float*)d_in[5];
  const float* C_re      = (const float*)d_in[6];
  const float* C_im      = (const float*)d_in[7];
  const float* D         = (const float*)d_in[8];
  float* out = (float*)d_out;

  char* ws = (char*)d_ws;
  constexpr size_t TH = (size_t)T_LEN * HID;       // 16.8M
  constexpr size_t W  = (size_t)1024 * 1024;
  constexpr size_t CH = (size_t)NCHUNK * HID;

  ushort* Xbf  = (ushort*)(ws);                    // TH*2
  ushort* Bu   = (ushort*)(ws + TH * 2);           // TH*2*2 (T x 2048)
  ushort* Hall = (ushort*)(ws + TH * 6);           // TH*2*2 (T x 2048)
  char*   p    = ws + TH * 10;
  ushort* Ball = (ushort*)(p);             p += 2 * W * 2;   // [BreT; BimT]
  ushort* CreB = (ushort*)(p);             p += W * 2;
  ushort* CimB = (ushort*)(p);             p += W * 2;
  ushort* DT   = (ushort*)(p);             p += W * 2;
  float*  Sre  = (float*)(p);              p += CH * 4;
  float*  Sim  = (float*)(p);              p += CH * 4;
  float*  Pre  = (float*)(p);              p += CH * 4;   // unused (kept for layout)
  float*  Pim  = (float*)(p);              p += CH * 4;   // unused (kept for layout)
  float*  lamR = (float*)(p);              p += 4096;
  float*  lamI = (float*)(p);              p += 4096;
  float*  eg   = (float*)(p);              p += 4096;     // unused (kept for layout)
  ushort* BreT = Ball;
  ushort* BimT = Ball + W;
  (void)Pre; (void)Pim; (void)eg;

  // z: 0,1 = B transpose+scale; 2,3 = C convert; 4 = D transpose;
  //    5 = lambda prep; 6..21 = convX (16 z-slices x 1024 blocks)
  prep_all<<<dim3(32, 32, 22), 256, 0, stream>>>(
      inputs, nu_log, theta_log, gamma_log, B_re, B_im, C_re, C_im, D,
      Xbf, BreT, BimT, CreB, CimB, DT, lamR, lamI);

  gemm_bu<<<dim3(512), 512, 0, stream>>>(Xbf, Ball, Bu);

  scan_sums<<<dim3(NCHUNK), 256, 0, stream>>>(Bu, lamR, lamI, Sre, Sim);
  scan_emit<<<dim3(NCHUNK), 256, 0, stream>>>(Bu, lamR, lamI, Sre, Sim, Hall);

  gemm3<<<dim3(256), 512, 0, stream>>>(Hall, CreB, CimB, Xbf, DT, out);
}